// Round 1
// 212.978 us; speedup vs baseline: 1.0592x; 1.0592x over previous
//
#include <hip/hip_runtime.h>
#include <hip/hip_bf16.h>

#define N_NODES 4096
#define N_EDGES 8192
#define N_GRAPHS 64
#define HDIM 128

typedef __attribute__((ext_vector_type(8))) short bf16x8;
typedef __attribute__((ext_vector_type(4))) float f32x4;
typedef __attribute__((ext_vector_type(4))) unsigned short u16x4;

static __device__ __forceinline__ unsigned short f2bf(float f) {
    unsigned u = __builtin_bit_cast(unsigned, f);
    u += 0x7fffu + ((u >> 16) & 1u);
    return (unsigned short)(u >> 16);
}
static __device__ __forceinline__ float bf2f(unsigned short s) {
    unsigned u = ((unsigned)s) << 16;
    return __builtin_bit_cast(float, u);
}

// ---------------- fused preprocessing: node MLP (+ bias path), edge MLP, w4 pack
// grid 896: [0,512) edge MLP, [512,768) node MLP, [768,896) pack
__global__ __launch_bounds__(256) void fused_pre_kernel(
    // node
    const float* __restrict__ x, const float* __restrict__ p1w, const float* __restrict__ p1b,
    const float* __restrict__ p2w, const float* __restrict__ p2b, const float* __restrict__ e4b,
    unsigned short* __restrict__ h_bf, float* __restrict__ hb,
    // edge
    const float* __restrict__ ea, const float* __restrict__ w1, const float* __restrict__ b1,
    const float* __restrict__ w2, const float* __restrict__ b2,
    const float* __restrict__ w3, const float* __restrict__ b3,
    unsigned short* __restrict__ e3bf,
    // pack
    const float* __restrict__ w4, unsigned short* __restrict__ w4perm)
{
    __shared__ __align__(16) char smem[33024];
    const int t = threadIdx.x;
    const int bid = blockIdx.x;

    if (bid < 512) {
        // ---- edge MLP: 5 -> 128 -> 256 -> 128, relu after each
        float (*es)[5]   = (float(*)[5])smem;            // 320 B
        float (*l1t)[16] = (float(*)[16])(smem + 320);   // 8192 B
        float (*l2t)[16] = (float(*)[16])(smem + 8512);  // 16384 B
        const int eb = bid * 16;

        for (int r = t; r < 80; r += 256) es[r / 5][r % 5] = ea[(eb + r / 5) * 5 + r % 5];
        __syncthreads();
        {
            int j = t & 127;
            float wd[5];
            #pragma unroll
            for (int d = 0; d < 5; ++d) wd[d] = w1[d * 128 + j];
            float bj = b1[j];
            for (int p = 0; p < 8; ++p) {
                int e = p * 2 + (t >> 7);
                float acc = bj;
                #pragma unroll
                for (int d = 0; d < 5; ++d) acc += es[e][d] * wd[d];
                l1t[j][e] = fmaxf(acc, 0.f);
            }
        }
        __syncthreads();
        {
            float acc[16];
            float bj = b2[t];
            #pragma unroll
            for (int r = 0; r < 16; ++r) acc[r] = bj;
            for (int k = 0; k < 128; ++k) {
                float w = w2[k * 256 + t];
                const float4* row = (const float4*)&l1t[k][0];
                float4 v0 = row[0], v1 = row[1], v2 = row[2], v3 = row[3];
                acc[0]  += v0.x * w; acc[1]  += v0.y * w; acc[2]  += v0.z * w; acc[3]  += v0.w * w;
                acc[4]  += v1.x * w; acc[5]  += v1.y * w; acc[6]  += v1.z * w; acc[7]  += v1.w * w;
                acc[8]  += v2.x * w; acc[9]  += v2.y * w; acc[10] += v2.z * w; acc[11] += v2.w * w;
                acc[12] += v3.x * w; acc[13] += v3.y * w; acc[14] += v3.z * w; acc[15] += v3.w * w;
            }
            #pragma unroll
            for (int r = 0; r < 16; ++r) l2t[t][r] = fmaxf(acc[r], 0.f);
        }
        __syncthreads();
        {
            int j = t & 127, eh = t >> 7;
            float acc[8];
            float bj = b3[j];
            #pragma unroll
            for (int r = 0; r < 8; ++r) acc[r] = bj;
            for (int k = 0; k < 256; ++k) {
                float w = w3[k * 128 + j];
                const float4* row = (const float4*)&l2t[k][eh * 8];
                float4 v0 = row[0], v1 = row[1];
                acc[0] += v0.x * w; acc[1] += v0.y * w; acc[2] += v0.z * w; acc[3] += v0.w * w;
                acc[4] += v1.x * w; acc[5] += v1.y * w; acc[6] += v1.z * w; acc[7] += v1.w * w;
            }
            #pragma unroll
            for (int r = 0; r < 8; ++r)
                e3bf[(eb + eh * 8 + r) * 128 + j] = f2bf(fmaxf(acc[r], 0.f));
        }
    } else if (bid < 768) {
        // ---- node MLP: h = relu(x@p1+b1)@p2+b2 ; hb = h @ B4
        float (*xs)[11]  = (float(*)[11])smem;           // 704 B
        float (*l1t)[16] = (float(*)[16])(smem + 704);   // 8192 B
        float (*hs)[16]  = (float(*)[16])(smem + 8896);  // 8192 B
        const int nb = bid - 512;

        for (int r = t; r < 16 * 11; r += 256) {
            int e = r / 11, d = r % 11;
            xs[e][d] = x[(nb * 16 + e) * 11 + d];
        }
        __syncthreads();
        {
            int j = t & 127;
            float wd[11];
            #pragma unroll
            for (int d = 0; d < 11; ++d) wd[d] = p1w[d * 128 + j];
            float bj = p1b[j];
            for (int p = 0; p < 8; ++p) {
                int e = p * 2 + (t >> 7);
                float acc = bj;
                #pragma unroll
                for (int d = 0; d < 11; ++d) acc += xs[e][d] * wd[d];
                l1t[j][e] = fmaxf(acc, 0.f);
            }
        }
        __syncthreads();
        {
            int j = t & 127, eh = t >> 7;
            float acc[8];
            float bj = p2b[j];
            #pragma unroll
            for (int r = 0; r < 8; ++r) acc[r] = bj;
            for (int k = 0; k < 128; ++k) {
                float w = p2w[k * 128 + j];
                const float4* row = (const float4*)&l1t[k][eh * 8];
                float4 v0 = row[0], v1 = row[1];
                acc[0] += v0.x * w; acc[1] += v0.y * w; acc[2] += v0.z * w; acc[3] += v0.w * w;
                acc[4] += v1.x * w; acc[5] += v1.y * w; acc[6] += v1.z * w; acc[7] += v1.w * w;
            }
            #pragma unroll
            for (int r = 0; r < 8; ++r) {
                int e = eh * 8 + r;
                h_bf[(nb * 16 + e) * 128 + j] = f2bf(acc[r]);
                hs[j][e] = acc[r];
            }
        }
        __syncthreads();
        {
            int j = t & 127, eh = t >> 7;
            float acc[8] = {0.f,0.f,0.f,0.f,0.f,0.f,0.f,0.f};
            for (int i = 0; i < 128; ++i) {
                float w = e4b[i * 128 + j];
                const float4* row = (const float4*)&hs[i][eh * 8];
                float4 v0 = row[0], v1 = row[1];
                acc[0] += v0.x * w; acc[1] += v0.y * w; acc[2] += v0.z * w; acc[3] += v0.w * w;
                acc[4] += v1.x * w; acc[5] += v1.y * w; acc[6] += v1.z * w; acc[7] += v1.w * w;
            }
            #pragma unroll
            for (int r = 0; r < 8; ++r) hb[(nb * 16 + eh * 8 + r) * 128 + j] = acc[r];
        }
    } else {
        // ---- pack e4_w into per-chunk bf16 [o][k] layout, k padded 128->136
        unsigned short (*tt)[129] = (unsigned short(*)[129])smem;  // 33024 B
        const int i = bid - 768;
        for (int r = t; r < 16384; r += 256) {
            int k = r >> 7, o = r & 127;
            tt[o][k] = f2bf(w4[k * 16384 + i * 128 + o]);
        }
        __syncthreads();
        for (int r = t; r < 16384; r += 256) {
            int o = r >> 7, k = r & 127;
            w4perm[i * 17408 + o * 136 + k] = tt[o][k];
        }
    }
}

// ---------------- fused NNConv message GEMM (double-buffered, XCD-local ksegs):
// msg[e,o] = sum_i h[src[e],i] * (E3[e,:] . w4[:, i*128+o]) ; scatter atomicAdd into agg[dst[e]]
// grid 512 linear: kseg = bid&7 (== XCD under round-robin dispatch -> chunk set L2-resident),
//                  etile = bid>>3
__global__ __launch_bounds__(256, 2) void nnconv_kernel(
    const unsigned short* __restrict__ e3bf, const unsigned short* __restrict__ h_bf,
    const unsigned short* __restrict__ w4perm, const float* __restrict__ hb,
    const int* __restrict__ ei, float* __restrict__ agg, float* __restrict__ cnt)
{
    __shared__ unsigned short ldsB[2 * 17408];   // double-buffered chunk: [o:128][k:136] bf16
    __shared__ unsigned short ht_t[16 * 128];    // TRANSPOSED: ht_t[c][row] (bank-conflict-free hv reads)
    const int t = threadIdx.x;
    const int bid = blockIdx.x;
    const int kseg  = bid & 7;
    const int etile = bid >> 3;
    const int w = t >> 6, lane = t & 63, q = lane >> 4, l15 = lane & 15;
    const int wm = (w & 1) * 64, wn = (w >> 1) * 64;
    const int e0 = etile * 128;
    const int i0 = kseg * 16;

    auto stage = [&](int buf, int chunk) {
        const char* src = (const char*)(w4perm + (size_t)chunk * 17408);
        char* dstl = (char*)ldsB + buf * 34816;
        #pragma unroll
        for (int it = 0; it < 9; ++it) {
            int off = it * 4096 + t * 16;
            if (off < 34816) {
                __builtin_amdgcn_global_load_lds(
                    (const __attribute__((address_space(1))) unsigned int*)(src + off),
                    (__attribute__((address_space(3))) unsigned int*)(dstl + off),
                    16, 0, 0);
            }
        }
    };

    // A fragments: e3 tile, constant across all K-chunks
    bf16x8 afrag[4][4];
    #pragma unroll
    for (int mb = 0; mb < 4; ++mb)
        #pragma unroll
        for (int s = 0; s < 4; ++s) {
            int row = e0 + wm + mb * 16 + l15;
            afrag[mb][s] = *(const bf16x8*)(e3bf + row * 128 + s * 32 + q * 8);
        }

    stage(0, i0);   // prefetch chunk 0 (overlaps ht staging + afrag loads)

    {   // gather h rows through src[e], store transposed: ht_t[c*128 + r]
        int r = t >> 1, part = t & 1;
        int s = ei[e0 + r];
        uint4 v = *(const uint4*)(h_bf + (size_t)s * 128 + i0 + part * 8);
        const unsigned short* pv = (const unsigned short*)&v;
        #pragma unroll
        for (int j = 0; j < 8; ++j) ht_t[(part * 8 + j) * 128 + r] = pv[j];
    }

    f32x4 acc[4][4];
    #pragma unroll
    for (int a_ = 0; a_ < 4; ++a_)
        #pragma unroll
        for (int b_ = 0; b_ < 4; ++b_)
            acc[a_][b_] = (f32x4){0.f, 0.f, 0.f, 0.f};
    const f32x4 zero4 = (f32x4){0.f, 0.f, 0.f, 0.f};

    __syncthreads();   // buf0 + ht_t ready

    auto compute = [&](const unsigned short* __restrict__ bbuf, int c) {
        float hv[4][4];
        #pragma unroll
        for (int mb = 0; mb < 4; ++mb) {
            u16x4 hr = *(const u16x4*)&ht_t[c * 128 + wm + mb * 16 + q * 4];  // one ds_read_b64
            #pragma unroll
            for (int r = 0; r < 4; ++r) hv[mb][r] = bf2f(hr[r]);
        }
        #pragma unroll
        for (int ob = 0; ob < 4; ++ob) {
            const int o = wn + ob * 16 + l15;
            bf16x8 bfrag[4];
            #pragma unroll
            for (int s = 0; s < 4; ++s)
                bfrag[s] = *(const bf16x8*)&bbuf[o * 136 + s * 32 + q * 8];
            #pragma unroll
            for (int mb = 0; mb < 4; ++mb) {
                f32x4 tmp = __builtin_amdgcn_mfma_f32_16x16x32_bf16(afrag[mb][0], bfrag[0], zero4, 0, 0, 0);
                tmp = __builtin_amdgcn_mfma_f32_16x16x32_bf16(afrag[mb][1], bfrag[1], tmp, 0, 0, 0);
                tmp = __builtin_amdgcn_mfma_f32_16x16x32_bf16(afrag[mb][2], bfrag[2], tmp, 0, 0, 0);
                tmp = __builtin_amdgcn_mfma_f32_16x16x32_bf16(afrag[mb][3], bfrag[3], tmp, 0, 0, 0);
                #pragma unroll
                for (int r = 0; r < 4; ++r)
                    acc[mb][ob][r] += hv[mb][r] * tmp[r];
            }
        }
    };

    // 2-phase pipeline: prefetch chunk c+1 while computing chunk c.
    // Barrier's vmcnt(0) drain only waits the REMAINDER of the prefetch.
    for (int cc = 0; cc < 16; cc += 2) {
        if (cc + 1 < 16) stage(1, i0 + cc + 1);
        compute(ldsB, cc);
        __syncthreads();
        if (cc + 2 < 16) stage(0, i0 + cc + 2);
        compute(ldsB + 17408, cc + 1);
        if (cc + 2 < 16) __syncthreads();
    }

    // epilogue: scatter into agg[dst[e]]; kseg 0 also adds bias-path hb[src[e]] and counts degree
    #pragma unroll
    for (int mb = 0; mb < 4; ++mb) {
        #pragma unroll
        for (int r = 0; r < 4; ++r) {
            int e = e0 + wm + mb * 16 + q * 4 + r;
            int de = ei[N_EDGES + e];
            int se = ei[e];
            if (kseg == 0 && wn == 0 && l15 == 0) atomicAdd(&cnt[de], 1.0f);
            #pragma unroll
            for (int ob = 0; ob < 4; ++ob) {
                int o = wn + ob * 16 + l15;
                float v = acc[mb][ob][r];
                if (kseg == 0) v += hb[(size_t)se * 128 + o];
                atomicAdd(&agg[(size_t)de * 128 + o], v);
            }
        }
    }
}

// ---------------- scatter-mean finalize + global add pool.
// batch is SORTED -> one block per graph, binary-search bounds, direct store (no atomics).
__global__ __launch_bounds__(128) void pool_kernel(
    const float* __restrict__ agg, const float* __restrict__ cnt,
    const int* __restrict__ batch, float* __restrict__ out)
{
    const int g = blockIdx.x, t = threadIdx.x;  // t = output channel o
    int lo = 0, hi = N_NODES;
    while (lo < hi) { int m = (lo + hi) >> 1; if (batch[m] < g) lo = m + 1; else hi = m; }
    const int n_lo = lo;
    int lo2 = n_lo, hi2 = N_NODES;
    while (lo2 < hi2) { int m = (lo2 + hi2) >> 1; if (batch[m] < g + 1) lo2 = m + 1; else hi2 = m; }
    const int n_hi = lo2;

    float s0 = 0.f, s1 = 0.f, s2 = 0.f, s3 = 0.f;
    int n = n_lo;
    for (; n + 4 <= n_hi; n += 4) {
        float c0 = cnt[n], c1 = cnt[n + 1], c2 = cnt[n + 2], c3 = cnt[n + 3];
        float v0 = agg[(n    ) * 128 + t];
        float v1 = agg[(n + 1) * 128 + t];
        float v2 = agg[(n + 2) * 128 + t];
        float v3 = agg[(n + 3) * 128 + t];
        s0 += v0 / (c0 > 1.f ? c0 : 1.f);
        s1 += v1 / (c1 > 1.f ? c1 : 1.f);
        s2 += v2 / (c2 > 1.f ? c2 : 1.f);
        s3 += v3 / (c3 > 1.f ? c3 : 1.f);
    }
    for (; n < n_hi; ++n) {
        float c = cnt[n];
        s0 += agg[n * 128 + t] / (c > 1.f ? c : 1.f);
    }
    out[g * 128 + t] = (s0 + s1) + (s2 + s3);
}

extern "C" void kernel_launch(void* const* d_in, const int* in_sizes, int n_in,
                              void* d_out, int out_size, void* d_ws, size_t ws_size,
                              hipStream_t stream)
{
    const float* x     = (const float*)d_in[0];
    const float* ea    = (const float*)d_in[1];
    const int*   ei    = (const int*)d_in[2];
    const int*   batch = (const int*)d_in[3];
    const float* p1w   = (const float*)d_in[4];
    const float* p1b   = (const float*)d_in[5];
    const float* p2w   = (const float*)d_in[6];
    const float* p2b   = (const float*)d_in[7];
    const float* w1    = (const float*)d_in[8];
    const float* b1    = (const float*)d_in[9];
    const float* w2    = (const float*)d_in[10];
    const float* b2    = (const float*)d_in[11];
    const float* w3    = (const float*)d_in[12];
    const float* b3    = (const float*)d_in[13];
    const float* w4    = (const float*)d_in[14];
    const float* b4    = (const float*)d_in[15];
    float* out = (float*)d_out;
    (void)in_sizes; (void)n_in; (void)out_size; (void)ws_size;

    char* ws = (char*)d_ws;
    unsigned short* h_bf = (unsigned short*)(ws);              // 1 MB
    unsigned short* e3bf = (unsigned short*)(ws + 1048576);    // 2 MB
    float* hb            = (float*)(ws + 3145728);             // 2 MB
    unsigned short* w4p  = (unsigned short*)(ws + 5242880);    // 4.25 MB (128*34816 B)
    float* agg           = (float*)(ws + 9699328);             // 2 MB
    float* cnt           = (float*)(ws + 11796480);            // 16 KB (contiguous after agg)

    // agg and cnt are contiguous -> single memset node
    hipMemsetAsync(agg, 0, (size_t)N_NODES * 128 * 4 + (size_t)N_NODES * 4, stream);

    fused_pre_kernel<<<896, 256, 0, stream>>>(
        x, p1w, p1b, p2w, p2b, b4, h_bf, hb,
        ea, w1, b1, w2, b2, w3, b3, e3bf,
        w4, w4p);
    nnconv_kernel<<<512, 256, 0, stream>>>(e3bf, h_bf, w4p, hb, ei, agg, cnt);
    pool_kernel<<<N_GRAPHS, 128, 0, stream>>>(agg, cnt, batch, out);
}

// Round 3
// 183.026 us; speedup vs baseline: 1.2326x; 1.1636x over previous
//
#include <hip/hip_runtime.h>
#include <hip/hip_bf16.h>

#define N_NODES 4096
#define N_EDGES 8192
#define N_GRAPHS 64
#define HDIM 128

typedef __attribute__((ext_vector_type(8))) short bf16x8;
typedef __attribute__((ext_vector_type(4))) float f32x4;
typedef __attribute__((ext_vector_type(4))) unsigned short u16x4;

static __device__ __forceinline__ unsigned short f2bf(float f) {
    unsigned u = __builtin_bit_cast(unsigned, f);
    u += 0x7fffu + ((u >> 16) & 1u);
    return (unsigned short)(u >> 16);
}
static __device__ __forceinline__ float bf2f(unsigned short s) {
    unsigned u = ((unsigned)s) << 16;
    return __builtin_bit_cast(float, u);
}

// ---------------- fused preprocessing: node MLP (+ bias path), edge MLP, w4 pack
// grid 896: [0,512) edge MLP, [512,768) node MLP, [768,896) pack
__global__ __launch_bounds__(256) void fused_pre_kernel(
    // node
    const float* __restrict__ x, const float* __restrict__ p1w, const float* __restrict__ p1b,
    const float* __restrict__ p2w, const float* __restrict__ p2b, const float* __restrict__ e4b,
    unsigned short* __restrict__ h_bf, float* __restrict__ hb,
    // edge
    const float* __restrict__ ea, const float* __restrict__ w1, const float* __restrict__ b1,
    const float* __restrict__ w2, const float* __restrict__ b2,
    const float* __restrict__ w3, const float* __restrict__ b3,
    unsigned short* __restrict__ e3bf,
    // pack
    const float* __restrict__ w4, unsigned short* __restrict__ w4perm)
{
    __shared__ __align__(16) char smem[33024];
    const int t = threadIdx.x;
    const int bid = blockIdx.x;

    if (bid < 512) {
        // ---- edge MLP: 5 -> 128 -> 256 -> 128, relu after each
        float (*es)[5]   = (float(*)[5])smem;            // 320 B
        float (*l1t)[16] = (float(*)[16])(smem + 320);   // 8192 B
        float (*l2t)[16] = (float(*)[16])(smem + 8512);  // 16384 B
        const int eb = bid * 16;

        for (int r = t; r < 80; r += 256) es[r / 5][r % 5] = ea[(eb + r / 5) * 5 + r % 5];
        __syncthreads();
        {
            int j = t & 127;
            float wd[5];
            #pragma unroll
            for (int d = 0; d < 5; ++d) wd[d] = w1[d * 128 + j];
            float bj = b1[j];
            for (int p = 0; p < 8; ++p) {
                int e = p * 2 + (t >> 7);
                float acc = bj;
                #pragma unroll
                for (int d = 0; d < 5; ++d) acc += es[e][d] * wd[d];
                l1t[j][e] = fmaxf(acc, 0.f);
            }
        }
        __syncthreads();
        {
            float acc[16];
            float bj = b2[t];
            #pragma unroll
            for (int r = 0; r < 16; ++r) acc[r] = bj;
            for (int k = 0; k < 128; ++k) {
                float w = w2[k * 256 + t];
                const float4* row = (const float4*)&l1t[k][0];
                float4 v0 = row[0], v1 = row[1], v2 = row[2], v3 = row[3];
                acc[0]  += v0.x * w; acc[1]  += v0.y * w; acc[2]  += v0.z * w; acc[3]  += v0.w * w;
                acc[4]  += v1.x * w; acc[5]  += v1.y * w; acc[6]  += v1.z * w; acc[7]  += v1.w * w;
                acc[8]  += v2.x * w; acc[9]  += v2.y * w; acc[10] += v2.z * w; acc[11] += v2.w * w;
                acc[12] += v3.x * w; acc[13] += v3.y * w; acc[14] += v3.z * w; acc[15] += v3.w * w;
            }
            #pragma unroll
            for (int r = 0; r < 16; ++r) l2t[t][r] = fmaxf(acc[r], 0.f);
        }
        __syncthreads();
        {
            int j = t & 127, eh = t >> 7;
            float acc[8];
            float bj = b3[j];
            #pragma unroll
            for (int r = 0; r < 8; ++r) acc[r] = bj;
            for (int k = 0; k < 256; ++k) {
                float w = w3[k * 128 + j];
                const float4* row = (const float4*)&l2t[k][eh * 8];
                float4 v0 = row[0], v1 = row[1];
                acc[0] += v0.x * w; acc[1] += v0.y * w; acc[2] += v0.z * w; acc[3] += v0.w * w;
                acc[4] += v1.x * w; acc[5] += v1.y * w; acc[6] += v1.z * w; acc[7] += v1.w * w;
            }
            #pragma unroll
            for (int r = 0; r < 8; ++r)
                e3bf[(eb + eh * 8 + r) * 128 + j] = f2bf(fmaxf(acc[r], 0.f));
        }
    } else if (bid < 768) {
        // ---- node MLP: h = relu(x@p1+b1)@p2+b2 ; hb = h @ B4
        float (*xs)[11]  = (float(*)[11])smem;           // 704 B
        float (*l1t)[16] = (float(*)[16])(smem + 704);   // 8192 B
        float (*hs)[16]  = (float(*)[16])(smem + 8896);  // 8192 B
        const int nb = bid - 512;

        for (int r = t; r < 16 * 11; r += 256) {
            int e = r / 11, d = r % 11;
            xs[e][d] = x[(nb * 16 + e) * 11 + d];
        }
        __syncthreads();
        {
            int j = t & 127;
            float wd[11];
            #pragma unroll
            for (int d = 0; d < 11; ++d) wd[d] = p1w[d * 128 + j];
            float bj = p1b[j];
            for (int p = 0; p < 8; ++p) {
                int e = p * 2 + (t >> 7);
                float acc = bj;
                #pragma unroll
                for (int d = 0; d < 11; ++d) acc += xs[e][d] * wd[d];
                l1t[j][e] = fmaxf(acc, 0.f);
            }
        }
        __syncthreads();
        {
            int j = t & 127, eh = t >> 7;
            float acc[8];
            float bj = p2b[j];
            #pragma unroll
            for (int r = 0; r < 8; ++r) acc[r] = bj;
            for (int k = 0; k < 128; ++k) {
                float w = p2w[k * 128 + j];
                const float4* row = (const float4*)&l1t[k][eh * 8];
                float4 v0 = row[0], v1 = row[1];
                acc[0] += v0.x * w; acc[1] += v0.y * w; acc[2] += v0.z * w; acc[3] += v0.w * w;
                acc[4] += v1.x * w; acc[5] += v1.y * w; acc[6] += v1.z * w; acc[7] += v1.w * w;
            }
            #pragma unroll
            for (int r = 0; r < 8; ++r) {
                int e = eh * 8 + r;
                h_bf[(nb * 16 + e) * 128 + j] = f2bf(acc[r]);
                hs[j][e] = acc[r];
            }
        }
        __syncthreads();
        {
            int j = t & 127, eh = t >> 7;
            float acc[8] = {0.f,0.f,0.f,0.f,0.f,0.f,0.f,0.f};
            for (int i = 0; i < 128; ++i) {
                float w = e4b[i * 128 + j];
                const float4* row = (const float4*)&hs[i][eh * 8];
                float4 v0 = row[0], v1 = row[1];
                acc[0] += v0.x * w; acc[1] += v0.y * w; acc[2] += v0.z * w; acc[3] += v0.w * w;
                acc[4] += v1.x * w; acc[5] += v1.y * w; acc[6] += v1.z * w; acc[7] += v1.w * w;
            }
            #pragma unroll
            for (int r = 0; r < 8; ++r) hb[(nb * 16 + eh * 8 + r) * 128 + j] = acc[r];
        }
    } else {
        // ---- pack e4_w into bf16 [osplit:4][chunk i:128][o_local:32][k:136] layout.
        // A block's (osplit, 64-chunk) slice is CONTIGUOUS -> full-wave global_load_lds only.
        unsigned short (*tt)[129] = (unsigned short(*)[129])smem;  // 33024 B
        const int i = bid - 768;
        for (int r = t; r < 16384; r += 256) {
            int k = r >> 7, o = r & 127;
            tt[o][k] = f2bf(w4[k * 16384 + i * 128 + o]);
        }
        __syncthreads();
        for (int r = t; r < 16384; r += 256) {
            int o = r >> 7, k = r & 127;
            w4perm[((size_t)(o >> 5) * 128 + i) * 4352 + (size_t)(o & 31) * 136 + k] = tt[o][k];
        }
    }
}

// ---------------- fused NNConv message GEMM, v3b: output-split instead of 8-way K-split.
// block = 128 edges x 32 out-cols x 64 chunks (half of K). Each (e,o) gets ONE atomic per
// K-half -> 2.1M atomics total (was 8.4M). bid&7 = XCD = (osplit,ksplit) so each XCD's
// B-slice (64 chunks x 8704 B = 557 KB, contiguous) is L2-resident.
// Wave tile 64e x 16o (mb=4): 4 MFMA per B ds_read_b128 (same LDS traffic as v2).
__global__ __launch_bounds__(256, 2) void nnconv_kernel(
    const unsigned short* __restrict__ e3bf, const unsigned short* __restrict__ h_bf,
    const unsigned short* __restrict__ w4perm, const float* __restrict__ hb,
    const int* __restrict__ ei, float* __restrict__ agg, float* __restrict__ cnt)
{
    __shared__ __align__(16) unsigned short ldsB[17408];  // 2 buf x (2 chunks x [32 o][136 k]) bf16
    __shared__ __align__(16) unsigned short ht_t[16384];  // ht_t[i][e] : [128 i][128 e] bf16
    const int t = threadIdx.x;
    const int bid = blockIdx.x;
    const int xcd    = bid & 7;
    const int osplit = xcd >> 1;       // 4 o-slices of 32
    const int ksplit = xcd & 1;        // 2 K-halves of 64 chunks
    const int etile  = bid >> 3;       // 64 tiles of 128 edges
    const int w = t >> 6, lane = t & 63, q = lane >> 4, l15 = lane & 15;
    const int mg = w >> 1;             // edge-group: mg*64
    const int og = w & 1;              // o-group within slice: og*16
    const int e0 = etile * 128;
    const int o0 = osplit * 32;
    const int k0 = ksplit * 64;

    // stage one chunk-PAIR slice (17408 B, contiguous in new w4perm layout) into buf.
    // 4 full 256-thread sweeps + one full-wave (t<64) sweep: no partial-wave exec.
    auto stage = [&](int buf, int gi) {
        const char* src = (const char*)w4perm + ((size_t)osplit * 128 + gi) * 8704;
        char* dst = (char*)ldsB + buf * 17408;
        #pragma unroll
        for (int it = 0; it < 4; ++it) {
            int off = it * 4096 + t * 16;
            __builtin_amdgcn_global_load_lds(
                (const __attribute__((address_space(1))) unsigned int*)(src + off),
                (__attribute__((address_space(3))) unsigned int*)(dst + off), 16, 0, 0);
        }
        if (t < 64) {   // wave-uniform: all of wave 0, none of waves 1-3
            int off = 16384 + t * 16;
            __builtin_amdgcn_global_load_lds(
                (const __attribute__((address_space(1))) unsigned int*)(src + off),
                (__attribute__((address_space(3))) unsigned int*)(dst + off), 16, 0, 0);
        }
    };

    stage(0, k0);   // prefetch chunks k0,k0+1 early (overlaps afrag + ht gather)

    // A fragments: e3 tile rows = this wave's 64 edges, constant across all chunks
    bf16x8 afrag[4][4];
    #pragma unroll
    for (int mb = 0; mb < 4; ++mb)
        #pragma unroll
        for (int s = 0; s < 4; ++s) {
            int row = e0 + mg * 64 + mb * 16 + l15;
            afrag[mb][s] = *(const bf16x8*)(e3bf + row * 128 + s * 32 + q * 8);
        }

    {   // gather h rows through src[e] for 128 edges, store transposed ht_t[i][e]
        int r = t >> 1, part = t & 1;            // 2 threads per edge, part covers i-halves
        int s = ei[e0 + r];
        #pragma unroll
        for (int u = 0; u < 8; ++u) {
            uint4 v = *(const uint4*)(h_bf + (size_t)s * 128 + part * 64 + u * 8);
            const unsigned short* pv = (const unsigned short*)&v;
            #pragma unroll
            for (int j = 0; j < 8; ++j) ht_t[(part * 64 + u * 8 + j) * 128 + r] = pv[j];
        }
    }

    f32x4 acc[4];
    #pragma unroll
    for (int mb = 0; mb < 4; ++mb) acc[mb] = (f32x4){0.f, 0.f, 0.f, 0.f};
    const f32x4 zero4 = (f32x4){0.f, 0.f, 0.f, 0.f};

    __syncthreads();   // buf0 + ht_t ready (barrier drains vmcnt)

    auto compute = [&](int bufbase /*u16 idx*/, int gi) {
        float hv[4][4];
        #pragma unroll
        for (int mb = 0; mb < 4; ++mb) {
            u16x4 hr = *(const u16x4*)&ht_t[gi * 128 + mg * 64 + mb * 16 + q * 4];
            #pragma unroll
            for (int r = 0; r < 4; ++r) hv[mb][r] = bf2f(hr[r]);
        }
        bf16x8 bfrag[4];
        #pragma unroll
        for (int s = 0; s < 4; ++s)
            bfrag[s] = *(const bf16x8*)&ldsB[bufbase + (og * 16 + l15) * 136 + s * 32 + q * 8];
        #pragma unroll
        for (int mb = 0; mb < 4; ++mb) {
            f32x4 tmp = __builtin_amdgcn_mfma_f32_16x16x32_bf16(afrag[mb][0], bfrag[0], zero4, 0, 0, 0);
            tmp = __builtin_amdgcn_mfma_f32_16x16x32_bf16(afrag[mb][1], bfrag[1], tmp, 0, 0, 0);
            tmp = __builtin_amdgcn_mfma_f32_16x16x32_bf16(afrag[mb][2], bfrag[2], tmp, 0, 0, 0);
            tmp = __builtin_amdgcn_mfma_f32_16x16x32_bf16(afrag[mb][3], bfrag[3], tmp, 0, 0, 0);
            #pragma unroll
            for (int r = 0; r < 4; ++r)
                acc[mb][r] += hv[mb][r] * tmp[r];
        }
    };

    // 32 phases x 2 chunks, double-buffered, one barrier per phase.
    int buf = 0;
    for (int p = 0; p < 32; ++p) {
        if (p + 1 < 32) stage(buf ^ 1, k0 + 2 * p + 2);
        compute(buf * 8704,        k0 + 2 * p);
        compute(buf * 8704 + 4352, k0 + 2 * p + 1);
        if (p + 1 < 32) __syncthreads();   // drains the prefetch + protects buf reuse
        buf ^= 1;
    }

    // epilogue: ONE atomic per (e,o) per K-half. ksplit 0 adds bias path hb[src[e]];
    // (osplit,ksplit,og)==0 lanes count degree.
    #pragma unroll
    for (int mb = 0; mb < 4; ++mb) {
        #pragma unroll
        for (int r = 0; r < 4; ++r) {
            int e = e0 + mg * 64 + mb * 16 + q * 4 + r;
            int de = ei[N_EDGES + e];
            int se = ei[e];
            if (xcd == 0 && og == 0 && l15 == 0) atomicAdd(&cnt[de], 1.0f);
            int o = o0 + og * 16 + l15;
            float v = acc[mb][r];
            if (ksplit == 0) v += hb[(size_t)se * 128 + o];
            atomicAdd(&agg[(size_t)de * 128 + o], v);
        }
    }
}

// ---------------- scatter-mean finalize + global add pool.
// batch is SORTED -> one block per graph, binary-search bounds, direct store (no atomics).
__global__ __launch_bounds__(128) void pool_kernel(
    const float* __restrict__ agg, const float* __restrict__ cnt,
    const int* __restrict__ batch, float* __restrict__ out)
{
    const int g = blockIdx.x, t = threadIdx.x;  // t = output channel o
    int lo = 0, hi = N_NODES;
    while (lo < hi) { int m = (lo + hi) >> 1; if (batch[m] < g) lo = m + 1; else hi = m; }
    const int n_lo = lo;
    int lo2 = n_lo, hi2 = N_NODES;
    while (lo2 < hi2) { int m = (lo2 + hi2) >> 1; if (batch[m] < g + 1) lo2 = m + 1; else hi2 = m; }
    const int n_hi = lo2;

    float s0 = 0.f, s1 = 0.f, s2 = 0.f, s3 = 0.f;
    int n = n_lo;
    for (; n + 4 <= n_hi; n += 4) {
        float c0 = cnt[n], c1 = cnt[n + 1], c2 = cnt[n + 2], c3 = cnt[n + 3];
        float v0 = agg[(n    ) * 128 + t];
        float v1 = agg[(n + 1) * 128 + t];
        float v2 = agg[(n + 2) * 128 + t];
        float v3 = agg[(n + 3) * 128 + t];
        s0 += v0 / (c0 > 1.f ? c0 : 1.f);
        s1 += v1 / (c1 > 1.f ? c1 : 1.f);
        s2 += v2 / (c2 > 1.f ? c2 : 1.f);
        s3 += v3 / (c3 > 1.f ? c3 : 1.f);
    }
    for (; n < n_hi; ++n) {
        float c = cnt[n];
        s0 += agg[n * 128 + t] / (c > 1.f ? c : 1.f);
    }
    out[g * 128 + t] = (s0 + s1) + (s2 + s3);
}

extern "C" void kernel_launch(void* const* d_in, const int* in_sizes, int n_in,
                              void* d_out, int out_size, void* d_ws, size_t ws_size,
                              hipStream_t stream)
{
    const float* x     = (const float*)d_in[0];
    const float* ea    = (const float*)d_in[1];
    const int*   ei    = (const int*)d_in[2];
    const int*   batch = (const int*)d_in[3];
    const float* p1w   = (const float*)d_in[4];
    const float* p1b   = (const float*)d_in[5];
    const float* p2w   = (const float*)d_in[6];
    const float* p2b   = (const float*)d_in[7];
    const float* w1    = (const float*)d_in[8];
    const float* b1    = (const float*)d_in[9];
    const float* w2    = (const float*)d_in[10];
    const float* b2    = (const float*)d_in[11];
    const float* w3    = (const float*)d_in[12];
    const float* b3    = (const float*)d_in[13];
    const float* w4    = (const float*)d_in[14];
    const float* b4    = (const float*)d_in[15];
    float* out = (float*)d_out;
    (void)in_sizes; (void)n_in; (void)out_size; (void)ws_size;

    char* ws = (char*)d_ws;
    unsigned short* h_bf = (unsigned short*)(ws);              // 1 MB
    unsigned short* e3bf = (unsigned short*)(ws + 1048576);    // 2 MB
    float* hb            = (float*)(ws + 3145728);             // 2 MB
    unsigned short* w4p  = (unsigned short*)(ws + 5242880);    // 4.25 MB (4456448 B)
    float* agg           = (float*)(ws + 9699328);             // 2 MB
    float* cnt           = (float*)(ws + 11796480);            // 16 KB (contiguous after agg)

    // agg and cnt are contiguous -> single memset node
    hipMemsetAsync(agg, 0, (size_t)N_NODES * 128 * 4 + (size_t)N_NODES * 4, stream);

    fused_pre_kernel<<<896, 256, 0, stream>>>(
        x, p1w, p1b, p2w, p2b, b4, h_bf, hb,
        ea, w1, b1, w2, b2, w3, b3, e3bf,
        w4, w4p);
    nnconv_kernel<<<512, 256, 0, stream>>>(e3bf, h_bf, w4p, hb, ei, agg, cnt);
    pool_kernel<<<N_GRAPHS, 128, 0, stream>>>(agg, cnt, batch, out);
}